// Round 14
// baseline (2214.848 us; speedup 1.0000x reference)
//
#include <hip/hip_runtime.h>

// f32-rounded scalars (jax weak-scalar semantics)
#define ALPHA_F ((float)0.8187307530779818)
#define BETA_F  ((float)0.9048374180359595)

// V6: NO global stores inside the t-loop. Spikes accumulate as per-thread bit
// masks (4 ch x 64 t = 8 VGPRs); one end-of-kernel burst flush writes each
// 256 B out row exactly once (V2's proven-clean wave-store shape, no
// interleaved loads). V3/V4/V5 showed 14-16x WRITE and ~64x FETCH (x evicted
// every t) with per-t stores at high concurrency, across 3 store flavors.
// Arithmetic chains bit-identical to V2..V5 (absmax 0.0).
__global__ __launch_bounds__(512) void snn_v6(
    const float* __restrict__ x, const float* __restrict__ wq,
    const float* __restrict__ bvec, float* __restrict__ out)
{
    __shared__ float wl[32][54];            // raw weights [o][ci*27+kt*9+kh*3+kw]
    __shared__ float wp[32][54];            // permuted    [o][((kt*3+kh)*3+kw)*2+ci]
    __shared__ __align__(16) float Dl[32][32];  // gram [cp][c]
    __shared__ float invl[32];
    __shared__ float biasl[32];
    __shared__ unsigned char msk[2][64][8]; // [parity][w][wave] spike nibbles

    const int tid = threadIdx.x;
    const int w  = tid & 63;
    const int wv = tid >> 6;        // 0..7
    const int c0 = wv * 4;          // my 4 channels
    const int idx = blockIdx.x;
    const int b = idx >> 6;
    const int h = ((idx & 7) << 3) | ((idx >> 3) & 7);  // XCD h-chunk swizzle

    // ---- stage weights ----
    for (int i = tid; i < 1728; i += 512) wl[i / 54][i % 54] = wq[i];
    __syncthreads();
    for (int i = tid; i < 1728; i += 512) {
        int c = i / 54, j = i % 54;
        int ci = j & 1, r = j >> 1;
        int kw_ = r % 3, kh_ = (r / 3) % 3, kt_ = r / 9;
        wp[c][j] = wl[c][ci * 27 + kt_ * 9 + kh_ * 3 + kw_];
    }
    for (int e = tid; e < 1024; e += 512) {
        int cp = e >> 5, c = e & 31;
        float s = 0.f;
        #pragma unroll
        for (int k = 0; k < 54; ++k) s = fmaf(wl[cp][k], wl[c][k], s);
        Dl[cp][c] = s;
    }
    __syncthreads();
    if (tid < 32) {
        float s = 0.f;
        #pragma unroll
        for (int k = 0; k < 54; ++k)
            s = __fadd_rn(s, __fmul_rn(wl[tid][k], wl[tid][k]));
        invl[tid] = 1.0f / __fadd_rn(s, 1e-8f);
        biasl[tid] = bvec[tid];
    }
    __syncthreads();

    float mem[4], syn[4];
    #pragma unroll
    for (int cl = 0; cl < 4; ++cl) { mem[cl] = 0.f; syn[cl] = 0.f; }
    unsigned mask = 0u;

    float inv_r[4], bias_r[4];
    #pragma unroll
    for (int cl = 0; cl < 4; ++cl) { inv_r[cl] = invl[c0 + cl]; bias_r[cl] = biasl[c0 + cl]; }

    // per-thread spike history: 4 channels x 64 t, as lo/hi 32-bit halves
    unsigned shist_lo[4] = {0u, 0u, 0u, 0u};
    unsigned shist_hi[4] = {0u, 0u, 0u, 0u};

    const size_t xb = (size_t)b * 524288;

    for (int t = 0; t < 64; ++t) {
        // ---- rst: fmaf(s, D, rst), s in {0,1}, cp ascending (bit-equal) ----
        float rst[4] = {0.f, 0.f, 0.f, 0.f};
        if (__ballot(mask != 0u)) {
            #pragma unroll
            for (int cp = 0; cp < 32; ++cp) {
                float s = ((mask >> cp) & 1u) ? 1.0f : 0.0f;
                const float4 dv = *(const float4*)&Dl[cp][c0];
                rst[0] = fmaf(s, dv.x, rst[0]);
                rst[1] = fmaf(s, dv.y, rst[1]);
                rst[2] = fmaf(s, dv.z, rst[2]);
                rst[3] = fmaf(s, dv.w, rst[3]);
            }
        }

        // ---- mem update (OLD syn), spike -> history bits + nibble ----
        const int par = t & 1;
        unsigned nib = 0u;
        #pragma unroll
        for (int cl = 0; cl < 4; ++cl) {
            float bm = __fmul_rn(BETA_F, mem[cl]);
            float bs = __fadd_rn(bm, syn[cl]);
            mem[cl] = __fsub_rn(bs, rst[cl]);
            float mthr = __fsub_rn(__fmul_rn(mem[cl], inv_r[cl]), bias_r[cl]);
            bool s = mthr > 0.f;
            nib |= (s ? 1u : 0u) << cl;
            if (t < 32) shist_lo[cl] |= (s ? 1u : 0u) << t;
            else        shist_hi[cl] |= (s ? 1u : 0u) << (t - 32);
        }
        msk[par][w][wv] = (unsigned char)nib;

        // ---- conv: per-channel single FMA chain, (kt,kh,kw,ci) order (== V2) ----
        float acc[4] = {0.f, 0.f, 0.f, 0.f};
        #pragma unroll
        for (int kt = 0; kt < 3; ++kt) {
            int tt = t + kt - 1;
            bool tok = (unsigned)tt < 64u;
            int ttc = tok ? tt : 0;
            #pragma unroll
            for (int kh = 0; kh < 3; ++kh) {
                int hh = h + kh - 1;
                bool hok = (unsigned)hh < 64u;
                int hhc = hok ? hh : 0;
                bool rowok = tok && hok;
                const float* rp0 = x + xb + (size_t)(ttc * 4096 + hhc * 64);
                const float* rp1 = rp0 + 262144;
                float x00 = (rowok && w > 0)  ? rp0[w - 1] : 0.f;
                float x01 = (rowok && w > 0)  ? rp1[w - 1] : 0.f;
                float x10 = rowok             ? rp0[w]     : 0.f;
                float x11 = rowok             ? rp1[w]     : 0.f;
                float x20 = (rowok && w < 63) ? rp0[w + 1] : 0.f;
                float x21 = (rowok && w < 63) ? rp1[w + 1] : 0.f;
                const int j0 = (kt * 3 + kh) * 6;
                #pragma unroll
                for (int cl = 0; cl < 4; ++cl) {
                    float a = acc[cl];
                    a = fmaf(x00, wp[c0 + cl][j0 + 0], a);
                    a = fmaf(x01, wp[c0 + cl][j0 + 1], a);
                    a = fmaf(x10, wp[c0 + cl][j0 + 2], a);
                    a = fmaf(x11, wp[c0 + cl][j0 + 3], a);
                    a = fmaf(x20, wp[c0 + cl][j0 + 4], a);
                    a = fmaf(x21, wp[c0 + cl][j0 + 5], a);
                    acc[cl] = a;
                }
            }
        }
        #pragma unroll
        for (int cl = 0; cl < 4; ++cl)
            syn[cl] = __fadd_rn(__fmul_rn(ALPHA_F, syn[cl]), acc[cl]);

        // ---- one barrier per t (parity-dbuf nibble exchange) ----
        __syncthreads();
        const uint2 mv = *(const uint2*)&msk[par][w][0];
        unsigned lo = (mv.x | (mv.x >> 4)) & 0x00FF00FFu;
        lo = (lo | (lo >> 8)) & 0xFFFFu;
        unsigned hi = (mv.y | (mv.y >> 4)) & 0x00FF00FFu;
        hi = (hi | (hi >> 8)) & 0xFFFFu;
        mask = lo | (hi << 16);
    }

    // ---- end-of-kernel burst flush: each 256 B row written exactly once ----
    #pragma unroll
    for (int cl = 0; cl < 4; ++cl) {
        float* op = out + (size_t)b * 8388608 + (size_t)(c0 + cl) * 262144
                  + (size_t)h * 64 + (size_t)w;
        unsigned lo = shist_lo[cl], hi = shist_hi[cl];
        for (int t = 0; t < 32; ++t)
            op[(size_t)t * 4096] = ((lo >> t) & 1u) ? 1.0f : 0.0f;
        for (int t = 0; t < 32; ++t)
            op[(size_t)(t + 32) * 4096] = ((hi >> t) & 1u) ? 1.0f : 0.0f;
    }
}

extern "C" void kernel_launch(void* const* d_in, const int* in_sizes, int n_in,
                              void* d_out, int out_size, void* d_ws, size_t ws_size,
                              hipStream_t stream) {
    const float* x  = (const float*)d_in[0];
    const float* wq = (const float*)d_in[1];
    const float* bv = (const float*)d_in[2];
    for (int i = 0; i < n_in; ++i) {
        int sz = in_sizes[i];
        if (sz == 8 * 2 * 64 * 64 * 64) x  = (const float*)d_in[i];
        else if (sz == 32 * 2 * 27)     wq = (const float*)d_in[i];
        else if (sz == 32)              bv = (const float*)d_in[i];
    }
    float* out = (float*)d_out;
    snn_v6<<<512, 512, 0, stream>>>(x, wq, bv, out);
}

// Round 15
// 405.778 us; speedup vs baseline: 5.4583x; 5.4583x over previous
//
#include <hip/hip_runtime.h>

// f32-rounded scalars (jax weak-scalar semantics)
#define ALPHA_F ((float)0.8187307530779818)
#define BETA_F  ((float)0.9048374180359595)

// V7: sliding-plane conv. Reference chain for output t is three 18-tap
// segments over planes t-1, t, t+1 (order kt,kh,kw,ci — ci fastest). Keep
// exact chain prefixes S1/S2 per channel; per t load ONLY plane t+1 (18
// x-values vs 54). Live-range cut kills the VGPR spills that V3..V6's
// counters exposed (3.7 GB invariant scratch writes at VGPR cap 128).
// All arithmetic bit-identical to the passing V2..V6 (absmax 0.0).
__global__ __launch_bounds__(512) void snn_v7(
    const float* __restrict__ x, const float* __restrict__ wq,
    const float* __restrict__ bvec, float* __restrict__ out)
{
    __shared__ float wl[32][54];            // raw weights [o][ci*27+kt*9+kh*3+kw]
    __shared__ float wps[3][32][18];        // [kt][o][jj], jj=(kh*3+kw)*2+ci
    __shared__ __align__(16) float Dl[32][32];  // gram [cp][c]
    __shared__ float invl[32];
    __shared__ float biasl[32];
    __shared__ unsigned char msk[2][64][8]; // [parity][w][wave] spike nibbles

    const int tid = threadIdx.x;
    const int w  = tid & 63;
    const int wv = tid >> 6;        // 0..7
    const int c0 = wv * 4;          // my 4 channels
    const int idx = blockIdx.x;
    const int b = idx >> 6;
    const int h = ((idx & 7) << 3) | ((idx >> 3) & 7);  // XCD h-chunk swizzle

    // ---- stage weights ----
    for (int i = tid; i < 1728; i += 512) wl[i / 54][i % 54] = wq[i];
    __syncthreads();
    // per-plane segment layout (chain order within a kt segment: kh,kw,ci)
    for (int i = tid; i < 1728; i += 512) {
        int c = i / 54, j = i % 54;          // j = kt*18 + jj
        int kt = j / 18, jj = j % 18;
        int ci = jj & 1, r = jj >> 1;        // r = kh*3+kw
        int kh = r / 3, kw = r % 3;
        wps[kt][c][jj] = wl[c][ci * 27 + kt * 9 + kh * 3 + kw];
    }
    // gram: sequential FMA chain, flat k ascending (== V2)
    for (int e = tid; e < 1024; e += 512) {
        int cp = e >> 5, c = e & 31;
        float s = 0.f;
        #pragma unroll
        for (int k = 0; k < 54; ++k) s = fmaf(wl[cp][k], wl[c][k], s);
        Dl[cp][c] = s;
    }
    __syncthreads();
    if (tid < 32) {
        float s = 0.f;
        #pragma unroll
        for (int k = 0; k < 54; ++k)
            s = __fadd_rn(s, __fmul_rn(wl[tid][k], wl[tid][k]));
        invl[tid] = 1.0f / __fadd_rn(s, 1e-8f);
        biasl[tid] = bvec[tid];
    }
    __syncthreads();

    float mem[4], syn[4], S1[4], S2[4];
    #pragma unroll
    for (int cl = 0; cl < 4; ++cl) { mem[cl] = 0.f; syn[cl] = 0.f; }
    unsigned mask = 0u;

    float inv_r[4], bias_r[4];
    #pragma unroll
    for (int cl = 0; cl < 4; ++cl) { inv_r[cl] = invl[c0 + cl]; bias_r[cl] = biasl[c0 + cl]; }

    const size_t xb = (size_t)b * 524288;
    const size_t ob = (size_t)b * 8388608 + (size_t)c0 * 262144 + (size_t)h * 64 + (size_t)w;

    float xv[18];
    // ---- gather plane `tt` (clamped); ok=false forces exact zero taps ----
    #define GATHER(TT, POK)                                                    \
    {                                                                          \
        const int tt = (TT);                                                   \
        _Pragma("unroll")                                                      \
        for (int kh = 0; kh < 3; ++kh) {                                       \
            int hh = h + kh - 1;                                               \
            bool hok = (unsigned)hh < 64u;                                     \
            int hhc = hok ? hh : 0;                                            \
            bool ok = (POK) && hok;                                            \
            const float* rp0 = x + xb + (size_t)(tt * 4096 + hhc * 64);        \
            const float* rp1 = rp0 + 262144;                                   \
            float a0 = rp0[(w > 0) ? (w - 1) : 0];                             \
            float a1 = rp0[w];                                                 \
            float a2 = rp0[(w < 63) ? (w + 1) : 63];                           \
            float b0 = rp1[(w > 0) ? (w - 1) : 0];                             \
            float b1 = rp1[w];                                                 \
            float b2 = rp1[(w < 63) ? (w + 1) : 63];                           \
            xv[(kh * 3 + 0) * 2 + 0] = (ok && w > 0)  ? a0 : 0.f;              \
            xv[(kh * 3 + 0) * 2 + 1] = (ok && w > 0)  ? b0 : 0.f;              \
            xv[(kh * 3 + 1) * 2 + 0] = ok ? a1 : 0.f;                          \
            xv[(kh * 3 + 1) * 2 + 1] = ok ? b1 : 0.f;                          \
            xv[(kh * 3 + 2) * 2 + 0] = (ok && w < 63) ? a2 : 0.f;              \
            xv[(kh * 3 + 2) * 2 + 1] = (ok && w < 63) ? b2 : 0.f;              \
        }                                                                      \
    }

    // ---- prologue: plane 0 -> S2 (kt=1 prefix), S1 (kt=0 prefix) ----
    GATHER(0, true);
    #pragma unroll
    for (int cl = 0; cl < 4; ++cl) {
        float a = 0.f;
        #pragma unroll
        for (int jj = 0; jj < 18; ++jj) a = fmaf(xv[jj], wps[1][c0 + cl][jj], a);
        S2[cl] = a;
        float s = 0.f;
        #pragma unroll
        for (int jj = 0; jj < 18; ++jj) s = fmaf(xv[jj], wps[0][c0 + cl][jj], s);
        S1[cl] = s;
    }

    for (int t = 0; t < 64; ++t) {
        // ---- rst: fmaf(s, D, rst), s in {0,1}, cp ascending (bit-equal) ----
        float rst[4] = {0.f, 0.f, 0.f, 0.f};
        if (__ballot(mask != 0u)) {
            #pragma unroll
            for (int cp = 0; cp < 32; ++cp) {
                float s = ((mask >> cp) & 1u) ? 1.0f : 0.0f;
                const float4 dv = *(const float4*)&Dl[cp][c0];
                rst[0] = fmaf(s, dv.x, rst[0]);
                rst[1] = fmaf(s, dv.y, rst[1]);
                rst[2] = fmaf(s, dv.z, rst[2]);
                rst[3] = fmaf(s, dv.w, rst[3]);
            }
        }

        // ---- mem update (OLD syn), spike, plain store, nibble ----
        const int par = t & 1;
        unsigned nib = 0u;
        #pragma unroll
        for (int cl = 0; cl < 4; ++cl) {
            float bm = __fmul_rn(BETA_F, mem[cl]);
            float bs = __fadd_rn(bm, syn[cl]);
            mem[cl] = __fsub_rn(bs, rst[cl]);
            float mthr = __fsub_rn(__fmul_rn(mem[cl], inv_r[cl]), bias_r[cl]);
            bool s = mthr > 0.f;
            nib |= (s ? 1u : 0u) << cl;
            out[ob + (size_t)cl * 262144 + (size_t)t * 4096] = s ? 1.0f : 0.0f;
        }
        msk[par][w][wv] = (unsigned char)nib;

        // ---- load plane t+1 (zeros past the end: exact padding no-ops) ----
        GATHER((t < 63) ? (t + 1) : 63, (t < 63));

        // ---- finish conv_t: acc = chain(S2, plane@kt2); advance prefixes ----
        float acc[4];
        #pragma unroll
        for (int cl = 0; cl < 4; ++cl) {
            float a = S2[cl];
            #pragma unroll
            for (int jj = 0; jj < 18; ++jj) a = fmaf(xv[jj], wps[2][c0 + cl][jj], a);
            acc[cl] = a;
        }
        #pragma unroll
        for (int cl = 0; cl < 4; ++cl) {
            float a = S1[cl];
            #pragma unroll
            for (int jj = 0; jj < 18; ++jj) a = fmaf(xv[jj], wps[1][c0 + cl][jj], a);
            S2[cl] = a;
            float s = 0.f;
            #pragma unroll
            for (int jj = 0; jj < 18; ++jj) s = fmaf(xv[jj], wps[0][c0 + cl][jj], s);
            S1[cl] = s;
        }
        #pragma unroll
        for (int cl = 0; cl < 4; ++cl)
            syn[cl] = __fadd_rn(__fmul_rn(ALPHA_F, syn[cl]), acc[cl]);

        // ---- one barrier per t (parity-dbuf nibble exchange) ----
        __syncthreads();
        const uint2 mv = *(const uint2*)&msk[par][w][0];
        unsigned lo = (mv.x | (mv.x >> 4)) & 0x00FF00FFu;
        lo = (lo | (lo >> 8)) & 0xFFFFu;
        unsigned hi = (mv.y | (mv.y >> 4)) & 0x00FF00FFu;
        hi = (hi | (hi >> 8)) & 0xFFFFu;
        mask = lo | (hi << 16);
    }
    #undef GATHER
}

extern "C" void kernel_launch(void* const* d_in, const int* in_sizes, int n_in,
                              void* d_out, int out_size, void* d_ws, size_t ws_size,
                              hipStream_t stream) {
    const float* x  = (const float*)d_in[0];
    const float* wq = (const float*)d_in[1];
    const float* bv = (const float*)d_in[2];
    for (int i = 0; i < n_in; ++i) {
        int sz = in_sizes[i];
        if (sz == 8 * 2 * 64 * 64 * 64) x  = (const float*)d_in[i];
        else if (sz == 32 * 2 * 27)     wq = (const float*)d_in[i];
        else if (sz == 32)              bv = (const float*)d_in[i];
    }
    float* out = (float*)d_out;
    snn_v7<<<512, 512, 0, stream>>>(x, wq, bv, out);
}

// Round 16
// 336.828 us; speedup vs baseline: 6.5756x; 1.2047x over previous
//
#include <hip/hip_runtime.h>

// f32-rounded scalars (jax weak-scalar semantics)
#define ALPHA_F ((float)0.8187307530779818)
#define BETA_F  ((float)0.9048374180359595)

// V8 = V7 (bit-exact, spill-free) with data movement restructured:
//  - x plane staged cooperatively into pre-padded LDS (zero per-tap VALU,
//    no boundary selects, 18 VMEM/thread -> 0.75 coalesced loads/thread)
//  - spike exchange as 0/1 floats in LDS (drops mask bit-twiddling; rst
//    reads s directly, fmaf(s,D,acc) chain unchanged -> bit-exact)
// One barrier per t; all parities disjoint across it (race-checked).
__global__ __launch_bounds__(512) void snn_v8(
    const float* __restrict__ x, const float* __restrict__ wq,
    const float* __restrict__ bvec, float* __restrict__ out)
{
    __shared__ float wl[32][54];            // raw weights
    __shared__ float wps[3][32][18];        // [kt][o][jj], jj=(kh*3+kw)*2+ci
    __shared__ __align__(16) float Dl[32][32];
    __shared__ float invl[32];
    __shared__ float biasl[32];
    __shared__ float spk[2][32][64];        // [parity][cp][w] spike floats
    __shared__ float xl[2][2][3][66];       // [parity][ci][kh][1+w], padded

    const int tid = threadIdx.x;
    const int w  = tid & 63;
    const int wv = tid >> 6;        // 0..7
    const int c0 = wv * 4;
    const int idx = blockIdx.x;
    const int b = idx >> 6;
    const int h = ((idx & 7) << 3) | ((idx >> 3) & 7);  // XCD h-chunk swizzle

    // ---- setup (identical arithmetic to V7) ----
    for (int i = tid; i < 1728; i += 512) wl[i / 54][i % 54] = wq[i];
    __syncthreads();
    for (int i = tid; i < 1728; i += 512) {
        int c = i / 54, j = i % 54;
        int kt = j / 18, jj = j % 18;
        int ci = jj & 1, r = jj >> 1;
        int kh = r / 3, kw = r % 3;
        wps[kt][c][jj] = wl[c][ci * 27 + kt * 9 + kh * 3 + kw];
    }
    for (int e = tid; e < 1024; e += 512) {
        int cp = e >> 5, c = e & 31;
        float s = 0.f;
        #pragma unroll
        for (int k = 0; k < 54; ++k) s = fmaf(wl[cp][k], wl[c][k], s);
        Dl[cp][c] = s;
    }
    for (int i = tid; i < 4096; i += 512) ((float*)spk)[i] = 0.f;
    if (tid < 24) {   // permanent zero pads: [p][ci][kh][0] and [65]
        int p = tid / 12, r = tid % 12;
        int ci = r / 6, kh = (r % 6) >> 1, end = r & 1;
        xl[p][ci][kh][end ? 65 : 0] = 0.f;
    }
    if (tid < 32) {
        float s = 0.f;
        #pragma unroll
        for (int k = 0; k < 54; ++k)
            s = __fadd_rn(s, __fmul_rn(wl[tid][k], wl[tid][k]));
        invl[tid] = 1.0f / __fadd_rn(s, 1e-8f);
        biasl[tid] = bvec[tid];
    }

    const size_t xb = (size_t)b * 524288;
    // stage mapping: tid<384 -> (ci, kh, w'); row invalid => zeros
    const int sci = (tid < 384) ? (tid / 192) : 0;
    const int skh = (tid < 384) ? ((tid % 192) / 64) : 0;
    const int sw  = tid & 63;
    const int shh = h + skh - 1;
    const bool srow_ok = (tid < 384) && ((unsigned)shh < 64u);
    const size_t sbase = xb + (size_t)sci * 262144 + (size_t)shh * 64 + sw;

    // prologue: stage plane 0 into xl[0]
    {
        float v = srow_ok ? x[sbase] : 0.f;
        if (tid < 384) xl[0][sci][skh][1 + sw] = v;
    }
    __syncthreads();

    float inv_r[4], bias_r[4];
    #pragma unroll
    for (int cl = 0; cl < 4; ++cl) { inv_r[cl] = invl[c0 + cl]; bias_r[cl] = biasl[c0 + cl]; }

    float xv[18];
    #define LOADXV(P)                                                          \
    {                                                                          \
        _Pragma("unroll")                                                      \
        for (int ci = 0; ci < 2; ++ci) {                                       \
            _Pragma("unroll")                                                  \
            for (int kh = 0; kh < 3; ++kh) {                                   \
                const float* row = &xl[P][ci][kh][w];                          \
                xv[(kh * 3 + 0) * 2 + ci] = row[0];                            \
                xv[(kh * 3 + 1) * 2 + ci] = row[1];                            \
                xv[(kh * 3 + 2) * 2 + ci] = row[2];                            \
            }                                                                  \
        }                                                                      \
    }

    // S1/S2 prefixes from plane 0 (exact chain prefixes, == V7)
    float S1[4], S2[4], mem[4], syn[4];
    LOADXV(0);
    #pragma unroll
    for (int cl = 0; cl < 4; ++cl) {
        float a = 0.f, s = 0.f;
        #pragma unroll
        for (int jj = 0; jj < 18; ++jj) a = fmaf(xv[jj], wps[1][c0 + cl][jj], a);
        S2[cl] = a;
        #pragma unroll
        for (int jj = 0; jj < 18; ++jj) s = fmaf(xv[jj], wps[0][c0 + cl][jj], s);
        S1[cl] = s;
        mem[cl] = 0.f; syn[cl] = 0.f;
    }

    const size_t ob = (size_t)b * 8388608 + (size_t)c0 * 262144 + (size_t)h * 64 + (size_t)w;

    for (int t = 0; t < 64; ++t) {
        const int pcur = t & 1;         // spikes of t; also xl buf holding plane t
        const int pnxt = (t + 1) & 1;   // spikes of t-1; xl buf for plane t+1

        // (1) issue stage load of plane t+1 early (hides under rst+scan)
        float sval = 0.f;
        if (srow_ok && t < 63) sval = x[sbase + (size_t)(t + 1) * 4096];

        // (2) rst from spk floats of t-1: fmaf(s,D,acc), cp ascending (bit-exact)
        float rst[4] = {0.f, 0.f, 0.f, 0.f};
        {
            const float* sp = &spk[pnxt][0][w];
            #pragma unroll
            for (int cp = 0; cp < 32; ++cp) {
                float s = sp[cp * 64];
                const float4 dv = *(const float4*)&Dl[cp][c0];
                rst[0] = fmaf(s, dv.x, rst[0]);
                rst[1] = fmaf(s, dv.y, rst[1]);
                rst[2] = fmaf(s, dv.z, rst[2]);
                rst[3] = fmaf(s, dv.w, rst[3]);
            }
        }

        // (3) mem update (OLD syn), spike, out store, spk write
        #pragma unroll
        for (int cl = 0; cl < 4; ++cl) {
            float bm = __fmul_rn(BETA_F, mem[cl]);
            float bs = __fadd_rn(bm, syn[cl]);
            mem[cl] = __fsub_rn(bs, rst[cl]);
            float mthr = __fsub_rn(__fmul_rn(mem[cl], inv_r[cl]), bias_r[cl]);
            float sf = (mthr > 0.f) ? 1.0f : 0.0f;
            spk[pcur][c0 + cl][w] = sf;
            out[ob + (size_t)cl * 262144 + (size_t)t * 4096] = sf;
        }

        // (4) write staged plane t+1
        if (tid < 384) xl[pnxt][sci][skh][1 + sw] = sval;

        // (5) the single barrier
        __syncthreads();

        // (6) conv: finish acc_t (S2 + kt2@plane t+1), advance prefixes (== V7)
        LOADXV(pnxt);
        float acc[4];
        #pragma unroll
        for (int cl = 0; cl < 4; ++cl) {
            float a = S2[cl];
            #pragma unroll
            for (int jj = 0; jj < 18; ++jj) a = fmaf(xv[jj], wps[2][c0 + cl][jj], a);
            acc[cl] = a;
        }
        #pragma unroll
        for (int cl = 0; cl < 4; ++cl) {
            float a = S1[cl], s = 0.f;
            #pragma unroll
            for (int jj = 0; jj < 18; ++jj) a = fmaf(xv[jj], wps[1][c0 + cl][jj], a);
            S2[cl] = a;
            #pragma unroll
            for (int jj = 0; jj < 18; ++jj) s = fmaf(xv[jj], wps[0][c0 + cl][jj], s);
            S1[cl] = s;
        }
        #pragma unroll
        for (int cl = 0; cl < 4; ++cl)
            syn[cl] = __fadd_rn(__fmul_rn(ALPHA_F, syn[cl]), acc[cl]);
    }
    #undef LOADXV
}

extern "C" void kernel_launch(void* const* d_in, const int* in_sizes, int n_in,
                              void* d_out, int out_size, void* d_ws, size_t ws_size,
                              hipStream_t stream) {
    const float* x  = (const float*)d_in[0];
    const float* wq = (const float*)d_in[1];
    const float* bv = (const float*)d_in[2];
    for (int i = 0; i < n_in; ++i) {
        int sz = in_sizes[i];
        if (sz == 8 * 2 * 64 * 64 * 64) x  = (const float*)d_in[i];
        else if (sz == 32 * 2 * 27)     wq = (const float*)d_in[i];
        else if (sz == 32)              bv = (const float*)d_in[i];
    }
    float* out = (float*)d_out;
    snn_v8<<<512, 512, 0, stream>>>(x, wq, bv, out);
}